// Round 1
// baseline (436.665 us; speedup 1.0000x reference)
//
#include <hip/hip_runtime.h>
#include <hip/hip_bf16.h>
#include <math.h>

#define BS 8
#define NPTS 1024
#define NH 8
#define FIN 256
#define FOUT 64
#define NEG_SLOPE 0.2f

// broadcast lane r's float to all lanes via v_readlane (SGPR result)
__device__ __forceinline__ float rdlane(float v, int r) {
  return __int_as_float(__builtin_amdgcn_readlane(__float_as_int(v), r));
}

// ---------------------------------------------------------------------------
// Adjacency dtype detector: writes flag=1 if adj is int32 {0,1}, 0 if bytes.
// Random 0/1 int32 words are always <=1; packed bool bytes reinterpreted as
// int32 are in {0,1} with prob 1/8 per word -> 256 words never all pass.
// ---------------------------------------------------------------------------
__global__ void detect_kernel(const unsigned int* __restrict__ adj,
                              int* __restrict__ flag) {
  __shared__ int bad;
  if (threadIdx.x == 0) bad = 0;
  __syncthreads();
  unsigned v = adj[threadIdx.x];  // 256 words = 1KB, safe for either layout
  if (v > 1u) bad = 1;
  __syncthreads();
  if (threadIdx.x == 0) *flag = bad ? 0 : 1;
}

// ---------------------------------------------------------------------------
// Projection: hp[b,h,i,o] = sum_k h[b,i,k] * w[h,k,o]
//             srcb[b,h,i] = sum_o tanh(hp) * a_src[h,o]   (dstb likewise)
// 1-wave blocks; lane = o; acc[r] = hp[i0+r][lane]. h row values broadcast
// from the lane whose index equals the row via v_readlane.
// ---------------------------------------------------------------------------
__global__ __launch_bounds__(64) void proj_kernel(
    const float* __restrict__ h, const float* __restrict__ w,
    const float* __restrict__ a_src, const float* __restrict__ a_dst,
    float* __restrict__ hp, float* __restrict__ srcb, float* __restrict__ dstb)
{
  const int lane = threadIdx.x;
  const int blk  = blockIdx.x;
  const int it = blk & 15;
  const int hh = (blk >> 4) & 7;
  const int b  = blk >> 7;
  const int i0 = it * 64;

  const float* hrow = h + (size_t)(b * NPTS + i0 + lane) * FIN;  // staging row
  const float* wb   = w + (size_t)hh * FIN * FOUT + lane;

  float acc[64];
#pragma unroll
  for (int r = 0; r < 64; ++r) acc[r] = 0.f;

  for (int k0 = 0; k0 < FIN; k0 += 8) {
    float hv[8];
    {
      float4 v0 = *(const float4*)(hrow + k0);
      float4 v1 = *(const float4*)(hrow + k0 + 4);
      hv[0]=v0.x; hv[1]=v0.y; hv[2]=v0.z; hv[3]=v0.w;
      hv[4]=v1.x; hv[5]=v1.y; hv[6]=v1.z; hv[7]=v1.w;
    }
    float wv[8];
#pragma unroll
    for (int kk = 0; kk < 8; ++kk)
      wv[kk] = wb[(size_t)(k0 + kk) * FOUT];   // coalesced over lanes
#pragma unroll
    for (int kk = 0; kk < 8; ++kk) {
#pragma unroll
      for (int r = 0; r < 64; ++r)
        acc[r] = fmaf(rdlane(hv[kk], r), wv[kk], acc[r]);
    }
  }

  // write hp (coalesced: 64 lanes x 4B per row)
  const int bh = b * NH + hh;
  const size_t obase = ((size_t)bh * NPTS + i0) * FOUT;
#pragma unroll
  for (int r = 0; r < 64; ++r)
    hp[obase + (size_t)r * FOUT + lane] = acc[r];

  // attn_src/attn_dst: per-row cross-lane reduction of tanh(hp)*a
  const float as = a_src[hh * FOUT + lane];
  const float ad = a_dst[hh * FOUT + lane];
  float my_src = 0.f, my_dst = 0.f;
#pragma unroll
  for (int r = 0; r < 64; ++r) {
    float t  = tanhf(acc[r]);
    float ps = t * as;
    float pd = t * ad;
#pragma unroll
    for (int m = 32; m >= 1; m >>= 1) {
      ps += __shfl_xor(ps, m, 64);
      pd += __shfl_xor(pd, m, 64);
    }
    if (lane == r) { my_src = ps; my_dst = pd; }
  }
  srcb[bh * NPTS + i0 + lane] = my_src;
  dstb[bh * NPTS + i0 + lane] = my_dst;
}

// ---------------------------------------------------------------------------
// Fused masked softmax + PV. 1-wave blocks, 64 rows per block, lane = o.
// Pass 1: row max (recomputable rank-1 logits). Pass 2: p=exp(lg-m), l+=p,
// acc[r] += p * hp[j][lane] with p broadcast via v_readlane.
// ---------------------------------------------------------------------------
template<int ISINT>
__global__ __launch_bounds__(64) void attn_kernel(
    const void* __restrict__ adjv, const float* __restrict__ hp,
    const float* __restrict__ srcb, const float* __restrict__ dstb,
    const float* __restrict__ bias, const int* __restrict__ flag,
    float* __restrict__ out)
{
  if (*flag != ISINT) return;   // uniform early-exit (wrong specialization)

  __shared__ float dsh[NPTS];
  const int lane = threadIdx.x;
  const int blk  = blockIdx.x;
  const int it = blk & 15;
  const int hh = (blk >> 4) & 7;
  const int b  = blk >> 7;
  const int i0 = it * 64;
  const int i  = i0 + lane;          // this thread's row
  const int bh = b * NH + hh;

  {
    const float4* s4 = (const float4*)(dstb + (size_t)bh * NPTS);
    float4* d4 = (float4*)dsh;
#pragma unroll
    for (int q = 0; q < NPTS / 4 / 64; ++q)
      d4[lane + q * 64] = s4[lane + q * 64];
  }
  __syncthreads();

  const int* adjI = (const int*)adjv;
  const unsigned char* adjB = (const unsigned char*)adjv;
  const size_t arow = ((size_t)b * NPTS + i) * NPTS;
  const float src_i = srcb[(size_t)bh * NPTS + i];

  // ---- pass 1: row max ----
  float m = -3.0e38f;
  for (int j0 = 0; j0 < NPTS; j0 += 8) {
    int a[8];
    if (ISINT) {
      int4 v0 = *(const int4*)(adjI + arow + j0);
      int4 v1 = *(const int4*)(adjI + arow + j0 + 4);
      a[0]=v0.x; a[1]=v0.y; a[2]=v0.z; a[3]=v0.w;
      a[4]=v1.x; a[5]=v1.y; a[6]=v1.z; a[7]=v1.w;
    } else {
      uint2 v = *(const uint2*)(adjB + arow + j0);
#pragma unroll
      for (int q = 0; q < 4; ++q) a[q]     = (v.x >> (8*q)) & 0xff;
#pragma unroll
      for (int q = 0; q < 4; ++q) a[q + 4] = (v.y >> (8*q)) & 0xff;
    }
#pragma unroll
    for (int jj = 0; jj < 8; ++jj) {
      int j = j0 + jj;
      float x = src_i + dsh[j];
      x = x >= 0.f ? x : NEG_SLOPE * x;
      bool valid = (a[jj] != 0) || (j == i);
      float lg = valid ? x : -3.0e38f;
      m = fmaxf(m, lg);
    }
  }

  // ---- pass 2: exp + sum + PV accumulate ----
  float acc[64];
#pragma unroll
  for (int r = 0; r < 64; ++r) acc[r] = 0.f;
  float l = 0.f;
  const float* hpb = hp + (size_t)bh * NPTS * FOUT;

  for (int j0 = 0; j0 < NPTS; j0 += 8) {
    int a[8];
    if (ISINT) {
      int4 v0 = *(const int4*)(adjI + arow + j0);
      int4 v1 = *(const int4*)(adjI + arow + j0 + 4);
      a[0]=v0.x; a[1]=v0.y; a[2]=v0.z; a[3]=v0.w;
      a[4]=v1.x; a[5]=v1.y; a[6]=v1.z; a[7]=v1.w;
    } else {
      uint2 v = *(const uint2*)(adjB + arow + j0);
#pragma unroll
      for (int q = 0; q < 4; ++q) a[q]     = (v.x >> (8*q)) & 0xff;
#pragma unroll
      for (int q = 0; q < 4; ++q) a[q + 4] = (v.y >> (8*q)) & 0xff;
    }
    float p[8];
#pragma unroll
    for (int jj = 0; jj < 8; ++jj) {
      int j = j0 + jj;
      float x = src_i + dsh[j];
      x = x >= 0.f ? x : NEG_SLOPE * x;
      bool valid = (a[jj] != 0) || (j == i);
      float e = valid ? __expf(x - m) : 0.f;
      p[jj] = e;
      l += e;
    }
    float hv[8];
#pragma unroll
    for (int jj = 0; jj < 8; ++jj)
      hv[jj] = hpb[(size_t)(j0 + jj) * FOUT + lane];   // coalesced
#pragma unroll
    for (int jj = 0; jj < 8; ++jj) {
#pragma unroll
      for (int r = 0; r < 64; ++r)
        acc[r] = fmaf(rdlane(p[jj], r), hv[jj], acc[r]);
    }
  }

  // ---- epilogue: normalize + bias ----
  const float bv = bias[lane];
  const size_t obase = ((size_t)bh * NPTS + i0) * FOUT;
#pragma unroll
  for (int r = 0; r < 64; ++r) {
    float lr = rdlane(l, r);
    out[obase + (size_t)r * FOUT + lane] = acc[r] / lr + bv;
  }
}

// ---------------------------------------------------------------------------
extern "C" void kernel_launch(void* const* d_in, const int* in_sizes, int n_in,
                              void* d_out, int out_size, void* d_ws, size_t ws_size,
                              hipStream_t stream)
{
  const float* h     = (const float*)d_in[0];
  const void*  adj   = d_in[1];
  const float* w     = (const float*)d_in[2];
  const float* a_src = (const float*)d_in[3];
  const float* a_dst = (const float*)d_in[4];
  const float* bias  = (const float*)d_in[5];
  float* out = (float*)d_out;

  // ws layout: [flag pad 256B][srcb 256KB][dstb 256KB][hp 16MB] = ~17.3MB
  int*   flag = (int*)d_ws;
  float* srcb = (float*)((char*)d_ws + 256);
  float* dstb = srcb + (size_t)BS * NH * NPTS;
  float* hp   = dstb + (size_t)BS * NH * NPTS;

  detect_kernel<<<1, 256, 0, stream>>>((const unsigned int*)adj, flag);
  proj_kernel<<<dim3(BS * NH * 16), dim3(64), 0, stream>>>(
      h, w, a_src, a_dst, hp, srcb, dstb);
  attn_kernel<1><<<dim3(BS * NH * 16), dim3(64), 0, stream>>>(
      adj, hp, srcb, dstb, bias, flag, out);
  attn_kernel<0><<<dim3(BS * NH * 16), dim3(64), 0, stream>>>(
      adj, hp, srcb, dstb, bias, flag, out);
}

// Round 2
// 217.081 us; speedup vs baseline: 2.0115x; 2.0115x over previous
//
#include <hip/hip_runtime.h>
#include <hip/hip_bf16.h>
#include <math.h>

#define BS 8
#define NPTS 1024
#define NH 8
#define FIN 256
#define FOUT 64
#define NEG_SLOPE 0.2f

typedef __attribute__((ext_vector_type(8))) short s8v;   // 8 bf16 (4 VGPR)
typedef __attribute__((ext_vector_type(4))) float f4v;   // 4 f32 acc

// f32 -> bf16 (RNE) as raw ushort; avoids hip_bf16.h ABI uncertainty
__device__ __forceinline__ unsigned short f2bf(float f) {
  unsigned u = __float_as_uint(f);
  unsigned r = (u + 0x7fffu + ((u >> 16) & 1u)) >> 16;
  return (unsigned short)r;
}
__device__ __forceinline__ float bf2f(unsigned short s) {
  return __uint_as_float(((unsigned)s) << 16);
}

// ---------------------------------------------------------------------------
// adj dtype detector (int32 {0,1} vs packed bytes)
// ---------------------------------------------------------------------------
__global__ void detect_kernel(const unsigned int* __restrict__ adj,
                              int* __restrict__ flag) {
  __shared__ int bad;
  if (threadIdx.x == 0) bad = 0;
  __syncthreads();
  unsigned v = adj[threadIdx.x];
  if (v > 1u) bad = 1;
  __syncthreads();
  if (threadIdx.x == 0) *flag = bad ? 0 : 1;
}

// ---------------------------------------------------------------------------
// w[h][k][o] -> wT_hi/lo[h][o][k] bf16 split (tiny)
// ---------------------------------------------------------------------------
__global__ void wsplit_kernel(const float* __restrict__ w,
                              unsigned short* __restrict__ wT_hi,
                              unsigned short* __restrict__ wT_lo) {
  const int hh = blockIdx.x;
  const int t = threadIdx.x;
  const int o = t & 63;
  const int kb = t >> 6;
  for (int k0 = 0; k0 < FIN; k0 += 4) {
    int k = k0 + kb;
    float v = w[((size_t)hh * FIN + k) * FOUT + o];
    unsigned short hi = f2bf(v);
    unsigned short lo = f2bf(v - bf2f(hi));
    wT_hi[((size_t)hh * FOUT + o) * FIN + k] = hi;
    wT_lo[((size_t)hh * FOUT + o) * FIN + k] = lo;
  }
}

// ---------------------------------------------------------------------------
// Projection via MFMA (3-term bf16 split == ~f32 precision).
// Block: (b,h, 64-row tile), 256 thr = 4 waves, wave w -> rows 16w..16w+15.
// Outputs: hpT_hi/lo[bh][o][j] bf16 (transposed via LDS), srcb/dstb f32.
// ---------------------------------------------------------------------------
__global__ __launch_bounds__(256, 2) void proj_kernel(
    const float* __restrict__ h, const unsigned short* __restrict__ wT_hi,
    const unsigned short* __restrict__ wT_lo,
    const float* __restrict__ a_src, const float* __restrict__ a_dst,
    unsigned short* __restrict__ hpT_hi, unsigned short* __restrict__ hpT_lo,
    float* __restrict__ srcb, float* __restrict__ dstb)
{
  __shared__ float tile[64][68];   // [row][o], pad 68 -> <=2-way conflicts

  const int t = threadIdx.x;
  const int lane = t & 63;
  const int wv = t >> 6;
  const int blk = blockIdx.x;
  const int it = blk & 15;
  const int hh = (blk >> 4) & 7;
  const int b  = blk >> 7;
  const int i0 = it * 64;
  const int bh = b * NH + hh;

  const int l15  = lane & 15;
  const int koff = (lane >> 4) * 8;
  const int arow = i0 + wv * 16 + l15;          // A-fragment row (global node)

  f4v acc[4];
#pragma unroll
  for (int nt = 0; nt < 4; ++nt) acc[nt] = 0.0f;

  const float* hrow = h + ((size_t)(b * NPTS + arow)) * FIN + koff;
  const unsigned short* wbase_hi = wT_hi + ((size_t)hh * FOUT + l15) * FIN + koff;
  const unsigned short* wbase_lo = wT_lo + ((size_t)hh * FOUT + l15) * FIN + koff;

  for (int k0 = 0; k0 < FIN; k0 += 32) {
    float4 a0 = *(const float4*)(hrow + k0);
    float4 a1 = *(const float4*)(hrow + k0 + 4);
    float av[8] = {a0.x, a0.y, a0.z, a0.w, a1.x, a1.y, a1.z, a1.w};
    s8v Ahi, Alo;
#pragma unroll
    for (int e = 0; e < 8; ++e) {
      unsigned short hi = f2bf(av[e]);
      Ahi[e] = (short)hi;
      Alo[e] = (short)f2bf(av[e] - bf2f(hi));
    }
#pragma unroll
    for (int nt = 0; nt < 4; ++nt) {
      s8v Bhi = *(const s8v*)(wbase_hi + (size_t)nt * 16 * FIN + k0);
      s8v Blo = *(const s8v*)(wbase_lo + (size_t)nt * 16 * FIN + k0);
      acc[nt] = __builtin_amdgcn_mfma_f32_16x16x32_bf16(Ahi, Bhi, acc[nt], 0, 0, 0);
      acc[nt] = __builtin_amdgcn_mfma_f32_16x16x32_bf16(Ahi, Blo, acc[nt], 0, 0, 0);
      acc[nt] = __builtin_amdgcn_mfma_f32_16x16x32_bf16(Alo, Bhi, acc[nt], 0, 0, 0);
    }
  }

  // ---- attn_src / attn_dst dots: tanh(hp) . a  (rows = 16w + (lane>>4)*4+q)
  float a_s[4], a_d[4];
#pragma unroll
  for (int nt = 0; nt < 4; ++nt) {
    a_s[nt] = a_src[hh * FOUT + nt * 16 + l15];
    a_d[nt] = a_dst[hh * FOUT + nt * 16 + l15];
  }
#pragma unroll
  for (int q = 0; q < 4; ++q) {
    float ps = 0.f, pd = 0.f;
#pragma unroll
    for (int nt = 0; nt < 4; ++nt) {
      float tv = tanhf(acc[nt][q]);
      ps = fmaf(tv, a_s[nt], ps);
      pd = fmaf(tv, a_d[nt], pd);
    }
#pragma unroll
    for (int m = 8; m >= 1; m >>= 1) {
      ps += __shfl_xor(ps, m, 64);
      pd += __shfl_xor(pd, m, 64);
    }
    if (l15 == 0) {
      int row = i0 + wv * 16 + (lane >> 4) * 4 + q;
      srcb[(size_t)bh * NPTS + row] = ps;
      dstb[(size_t)bh * NPTS + row] = pd;
    }
  }

  // ---- hpT store: acc -> LDS [row][o] -> transposed read -> bf16 hi/lo
#pragma unroll
  for (int nt = 0; nt < 4; ++nt)
#pragma unroll
    for (int q = 0; q < 4; ++q)
      tile[wv * 16 + (lane >> 4) * 4 + q][nt * 16 + l15] = acc[nt][q];
  __syncthreads();

  const int orow = t >> 2;          // output o-row
  const int jseg = t & 3;           // 16-j segment
  unsigned short hbuf[16], lbuf[16];
#pragma unroll
  for (int q = 0; q < 16; ++q) {
    float v = tile[jseg * 16 + q][orow];
    unsigned short hi = f2bf(v);
    hbuf[q] = hi;
    lbuf[q] = f2bf(v - bf2f(hi));
  }
  size_t obase = ((size_t)(bh * FOUT + orow)) * NPTS + i0 + jseg * 16;
  *(uint4*)(hpT_hi + obase)     = *(const uint4*)&hbuf[0];
  *(uint4*)(hpT_hi + obase + 8) = *(const uint4*)&hbuf[8];
  *(uint4*)(hpT_lo + obase)     = *(const uint4*)&lbuf[0];
  *(uint4*)(hpT_lo + obase + 8) = *(const uint4*)&lbuf[8];
}

// ---------------------------------------------------------------------------
// Fused masked softmax + PV via MFMA.
// Block: (b,h, 64-row tile), 256 thr = 4 waves.
// Single adj pass: m_row = leaky(src_i + max_all_j dst_j) >= true row max.
// P tile (64x64) bf16 in padded LDS; B-frags direct from global hpT (L2).
// ---------------------------------------------------------------------------
template<int ISINT>
__global__ __launch_bounds__(256, 2) void attn_kernel(
    const void* __restrict__ adjv,
    const unsigned short* __restrict__ hpT_hi,
    const unsigned short* __restrict__ hpT_lo,
    const float* __restrict__ srcb, const float* __restrict__ dstb,
    const float* __restrict__ bias, const int* __restrict__ flag,
    float* __restrict__ out)
{
  if (*flag != ISINT) return;

  __shared__ float dsh[NPTS];
  __shared__ unsigned short p_sh[64][72];   // +16B pad per row
  __shared__ float l_sh[64];
  __shared__ float wred[4];

  const int t = threadIdx.x;
  const int lane = t & 63;
  const int wv = t >> 6;
  const int blk = blockIdx.x;
  const int it = blk & 15;
  const int hh = (blk >> 4) & 7;
  const int b  = blk >> 7;
  const int i0 = it * 64;
  const int bh = b * NH + hh;

  // ---- prologue: dst -> LDS, global dst max M
  float4 dv = ((const float4*)(dstb + (size_t)bh * NPTS))[t];
  ((float4*)dsh)[t] = dv;
  float lm = fmaxf(fmaxf(dv.x, dv.y), fmaxf(dv.z, dv.w));
#pragma unroll
  for (int m = 32; m >= 1; m >>= 1) lm = fmaxf(lm, __shfl_xor(lm, m, 64));
  if (lane == 0) wred[wv] = lm;
  __syncthreads();
  const float M = fmaxf(fmaxf(wred[0], wred[1]), fmaxf(wred[2], wred[3]));

  const int r = t >> 2;             // this thread's row (0..63)
  const int c = t & 3;              // 16-j segment
  const int i = i0 + r;             // global row
  const float src_r = srcb[(size_t)bh * NPTS + i];
  const float xm = src_r + M;
  const float m_row = xm >= 0.f ? xm : NEG_SLOPE * xm;

  const int* adjI = (const int*)adjv;
  const unsigned char* adjB = (const unsigned char*)adjv;
  const size_t arow = ((size_t)(b * NPTS + i)) * NPTS + c * 16;

  const int l15  = lane & 15;
  const int koff = (lane >> 4) * 8;
  const int prow = wv * 16 + l15;   // A-fragment row in p_sh
  const unsigned short* bb_hi = hpT_hi + ((size_t)(bh * FOUT + l15)) * NPTS + koff;
  const unsigned short* bb_lo = hpT_lo + ((size_t)(bh * FOUT + l15)) * NPTS + koff;

  float l = 0.f;
  f4v acc[4];
#pragma unroll
  for (int nt = 0; nt < 4; ++nt) acc[nt] = 0.0f;

  for (int j0 = 0; j0 < NPTS; j0 += 64) {
    // adj (issued first), then B-frag prefetch — both in flight under P VALU
    int a[16];
    if (ISINT) {
      int4 v0 = *(const int4*)(adjI + arow + j0);
      int4 v1 = *(const int4*)(adjI + arow + j0 + 4);
      int4 v2 = *(const int4*)(adjI + arow + j0 + 8);
      int4 v3 = *(const int4*)(adjI + arow + j0 + 12);
      a[0]=v0.x; a[1]=v0.y; a[2]=v0.z; a[3]=v0.w;
      a[4]=v1.x; a[5]=v1.y; a[6]=v1.z; a[7]=v1.w;
      a[8]=v2.x; a[9]=v2.y; a[10]=v2.z; a[11]=v2.w;
      a[12]=v3.x; a[13]=v3.y; a[14]=v3.z; a[15]=v3.w;
    } else {
      uint4 v = *(const uint4*)(adjB + arow + j0);
#pragma unroll
      for (int q = 0; q < 4; ++q) a[q]      = (v.x >> (q * 8)) & 0xff;
#pragma unroll
      for (int q = 0; q < 4; ++q) a[q + 4]  = (v.y >> (q * 8)) & 0xff;
#pragma unroll
      for (int q = 0; q < 4; ++q) a[q + 8]  = (v.z >> (q * 8)) & 0xff;
#pragma unroll
      for (int q = 0; q < 4; ++q) a[q + 12] = (v.w >> (q * 8)) & 0xff;
    }

    s8v Bh[2][4], Bl[2][4];
#pragma unroll
    for (int ks = 0; ks < 2; ++ks)
#pragma unroll
      for (int nt = 0; nt < 4; ++nt) {
        Bh[ks][nt] = *(const s8v*)(bb_hi + (size_t)nt * 16 * NPTS + j0 + ks * 32);
        Bl[ks][nt] = *(const s8v*)(bb_lo + (size_t)nt * 16 * NPTS + j0 + ks * 32);
      }

    // ---- P compute (16 logits/thread)
    unsigned short pb[16];
#pragma unroll
    for (int q = 0; q < 16; ++q) {
      int j = j0 + c * 16 + q;
      float x = src_r + dsh[j];
      x = x >= 0.f ? x : NEG_SLOPE * x;
      bool valid = (a[q] != 0) || (j == i);
      if (valid) {
        unsigned short pw = f2bf(__expf(x - m_row));
        pb[q] = pw;
        l += bf2f(pw);             // sum the ROUNDED p (consistency with PV)
      } else {
        pb[q] = 0;
      }
    }

    __syncthreads();               // previous MFMA phase done reading p_sh
    *(uint4*)&p_sh[r][c * 16]     = *(const uint4*)&pb[0];
    *(uint4*)&p_sh[r][c * 16 + 8] = *(const uint4*)&pb[8];
    __syncthreads();               // P tile ready

    // ---- MFMA phase: acc += P * (hp_hi + hp_lo)
#pragma unroll
    for (int ks = 0; ks < 2; ++ks) {
      s8v A = *(const s8v*)&p_sh[prow][ks * 32 + koff];
#pragma unroll
      for (int nt = 0; nt < 4; ++nt) {
        acc[nt] = __builtin_amdgcn_mfma_f32_16x16x32_bf16(A, Bh[ks][nt], acc[nt], 0, 0, 0);
        acc[nt] = __builtin_amdgcn_mfma_f32_16x16x32_bf16(A, Bl[ks][nt], acc[nt], 0, 0, 0);
      }
    }
  }

  // ---- l: sum partials across the 4 threads sharing a row
  l += __shfl_xor(l, 1, 64);
  l += __shfl_xor(l, 2, 64);
  if ((lane & 3) == 0) l_sh[wv * 16 + (lane >> 2)] = l;
  __syncthreads();

  float bias4[4];
#pragma unroll
  for (int nt = 0; nt < 4; ++nt) bias4[nt] = bias[nt * 16 + l15];

#pragma unroll
  for (int q = 0; q < 4; ++q) {
    int row = wv * 16 + (lane >> 4) * 4 + q;
    float linv = 1.0f / l_sh[row];
    size_t ob = ((size_t)bh * NPTS + i0 + row) * FOUT;
#pragma unroll
    for (int nt = 0; nt < 4; ++nt)
      out[ob + nt * 16 + l15] = acc[nt][q] * linv + bias4[nt];
  }
}

// ---------------------------------------------------------------------------
extern "C" void kernel_launch(void* const* d_in, const int* in_sizes, int n_in,
                              void* d_out, int out_size, void* d_ws, size_t ws_size,
                              hipStream_t stream)
{
  const float* h     = (const float*)d_in[0];
  const void*  adj   = d_in[1];
  const float* w     = (const float*)d_in[2];
  const float* a_src = (const float*)d_in[3];
  const float* a_dst = (const float*)d_in[4];
  const float* bias  = (const float*)d_in[5];
  float* out = (float*)d_out;

  // ws layout (16B-aligned chunks), total ~17.0 MB
  char* p = (char*)d_ws;
  int* flag = (int*)p;                          p += 256;
  float* srcb = (float*)p;                      p += (size_t)BS * NH * NPTS * 4;
  float* dstb = (float*)p;                      p += (size_t)BS * NH * NPTS * 4;
  unsigned short* wT_hi = (unsigned short*)p;   p += (size_t)NH * FOUT * FIN * 2;
  unsigned short* wT_lo = (unsigned short*)p;   p += (size_t)NH * FOUT * FIN * 2;
  unsigned short* hpT_hi = (unsigned short*)p;  p += (size_t)BS * NH * FOUT * NPTS * 2;
  unsigned short* hpT_lo = (unsigned short*)p;

  detect_kernel<<<1, 256, 0, stream>>>((const unsigned int*)adj, flag);
  wsplit_kernel<<<NH, 256, 0, stream>>>(w, wT_hi, wT_lo);
  proj_kernel<<<dim3(BS * NH * 16), dim3(256), 0, stream>>>(
      h, wT_hi, wT_lo, a_src, a_dst, hpT_hi, hpT_lo, srcb, dstb);
  attn_kernel<1><<<dim3(BS * NH * 16), dim3(256), 0, stream>>>(
      adj, hpT_hi, hpT_lo, srcb, dstb, bias, flag, out);
  attn_kernel<0><<<dim3(BS * NH * 16), dim3(256), 0, stream>>>(
      adj, hpT_hi, hpT_lo, srcb, dstb, bias, flag, out);
}

// Round 3
// 119.767 us; speedup vs baseline: 3.6459x; 1.8125x over previous
//
#include <hip/hip_runtime.h>
#include <hip/hip_bf16.h>
#include <math.h>

#define BS 8
#define NPTS 1024
#define NH 8
#define FIN 256
#define FOUT 64

typedef __attribute__((ext_vector_type(8))) short s8v;       // 8 bf16
typedef __attribute__((ext_vector_type(8))) _Float16 h8v;    // 8 f16
typedef __attribute__((ext_vector_type(4))) float f4v;       // 4 f32 acc

__device__ __forceinline__ unsigned short f2bf(float f) {
  unsigned u = __float_as_uint(f);
  return (unsigned short)((u + 0x7fffu + ((u >> 16) & 1u)) >> 16);
}
__device__ __forceinline__ float bf2f(unsigned short s) {
  return __uint_as_float(((unsigned)s) << 16);
}
__device__ __forceinline__ float fast_tanh(float x) {
  float e = __expf(2.f * x);          // inf-safe: x>>0 -> 1, x<<0 -> -1
  return 1.f - 2.f / (e + 1.f);
}

// ---------------------------------------------------------------------------
// adj dtype detector (int32 {0,1} vs packed bytes)
// ---------------------------------------------------------------------------
__global__ void detect_kernel(const unsigned int* __restrict__ adj,
                              int* __restrict__ flag) {
  __shared__ int bad;
  if (threadIdx.x == 0) bad = 0;
  __syncthreads();
  unsigned v = adj[threadIdx.x];
  if (v > 1u) bad = 1;
  __syncthreads();
  if (threadIdx.x == 0) *flag = bad ? 0 : 1;
}

// ---------------------------------------------------------------------------
// adj -> bitmask, diagonal folded in. abits[b][i][16] u64 (1 MB total).
// One wave produces 32 u64 words via __ballot.
// ---------------------------------------------------------------------------
template<int ISINT>
__global__ __launch_bounds__(256) void pack_kernel(
    const void* __restrict__ adjv, const int* __restrict__ flag,
    unsigned long long* __restrict__ abits)
{
  if (*flag != ISINT) return;
  const int gw = blockIdx.x * 4 + (threadIdx.x >> 6);   // wave id 0..4095
  const int lane = threadIdx.x & 63;
  const int w0 = gw * 32;
#pragma unroll 4
  for (int q = 0; q < 32; ++q) {
    int wI = w0 + q;
    int b  = wI >> 14;
    int i  = (wI >> 4) & 1023;
    int ch = wI & 15;
    int j  = ch * 64 + lane;
    int a;
    if (ISINT) a = ((const int*)adjv)[((size_t)b * NPTS + i) * NPTS + j];
    else       a = ((const unsigned char*)adjv)[((size_t)b * NPTS + i) * NPTS + j];
    unsigned long long m = __ballot(a != 0 || j == i);
    if (lane == 0) abits[wI] = m;
  }
}

// ---------------------------------------------------------------------------
// w[h][k][o] -> wT_hi/lo[h][o][k] bf16 split
// ---------------------------------------------------------------------------
__global__ void wsplit_kernel(const float* __restrict__ w,
                              unsigned short* __restrict__ wT_hi,
                              unsigned short* __restrict__ wT_lo) {
  const int hh = blockIdx.x;
  const int t = threadIdx.x;
  const int o = t & 63;
  const int kb = t >> 6;
  for (int k0 = 0; k0 < FIN; k0 += 4) {
    int k = k0 + kb;
    float v = w[((size_t)hh * FIN + k) * FOUT + o];
    unsigned short hi = f2bf(v);
    unsigned short lo = f2bf(v - bf2f(hi));
    wT_hi[((size_t)hh * FOUT + o) * FIN + k] = hi;
    wT_lo[((size_t)hh * FOUT + o) * FIN + k] = lo;
  }
}

// ---------------------------------------------------------------------------
// Projection via MFMA (3-term bf16 split ~ f32 precision).
// Outputs: hfrag f16 fragment-major per (bh, j-tile):
//   hfrag[bh][jt][c= ks*4+nt][lane][8]  value = hp[jt*64+ks*32+(lane>>4)*8+e][nt*16+(lane&15)]
// plus srcb/dstb f32.
// ---------------------------------------------------------------------------
__global__ __launch_bounds__(256, 2) void proj_kernel(
    const float* __restrict__ h, const unsigned short* __restrict__ wT_hi,
    const unsigned short* __restrict__ wT_lo,
    const float* __restrict__ a_src, const float* __restrict__ a_dst,
    unsigned short* __restrict__ hfrag,
    float* __restrict__ srcb, float* __restrict__ dstb)
{
  __shared__ float tile[64][65];   // pad 65: transpose reads ~conflict-free

  const int t = threadIdx.x;
  const int lane = t & 63;
  const int wv = t >> 6;
  const int blk = blockIdx.x;
  const int it = blk & 15;
  const int hh = (blk >> 4) & 7;
  const int b  = blk >> 7;
  const int i0 = it * 64;
  const int bh = b * NH + hh;
  const int l15 = lane & 15;
  const int koff = (lane >> 4) * 8;

  f4v acc[4];
#pragma unroll
  for (int nt = 0; nt < 4; ++nt) acc[nt] = 0.0f;

  const float* hrow = h + ((size_t)(b * NPTS + i0 + wv * 16 + l15)) * FIN + koff;
  const unsigned short* wh = wT_hi + ((size_t)hh * FOUT + l15) * FIN + koff;
  const unsigned short* wl = wT_lo + ((size_t)hh * FOUT + l15) * FIN + koff;

#pragma unroll
  for (int k0 = 0; k0 < FIN; k0 += 32) {
    float4 a0 = *(const float4*)(hrow + k0);
    float4 a1 = *(const float4*)(hrow + k0 + 4);
    float av[8] = {a0.x, a0.y, a0.z, a0.w, a1.x, a1.y, a1.z, a1.w};
    s8v Ahi, Alo;
#pragma unroll
    for (int e = 0; e < 8; ++e) {
      unsigned short hi = f2bf(av[e]);
      Ahi[e] = (short)hi;
      Alo[e] = (short)f2bf(av[e] - bf2f(hi));
    }
#pragma unroll
    for (int nt = 0; nt < 4; ++nt) {
      s8v Bhi = *(const s8v*)(wh + (size_t)nt * 16 * FIN + k0);
      s8v Blo = *(const s8v*)(wl + (size_t)nt * 16 * FIN + k0);
      acc[nt] = __builtin_amdgcn_mfma_f32_16x16x32_bf16(Ahi, Bhi, acc[nt], 0, 0, 0);
      acc[nt] = __builtin_amdgcn_mfma_f32_16x16x32_bf16(Ahi, Blo, acc[nt], 0, 0, 0);
      acc[nt] = __builtin_amdgcn_mfma_f32_16x16x32_bf16(Alo, Bhi, acc[nt], 0, 0, 0);
    }
  }

  // ---- attn_src / attn_dst: tanh(hp) . a  (rows = wv*16 + (lane>>4)*4+q)
  float a_s[4], a_d[4];
#pragma unroll
  for (int nt = 0; nt < 4; ++nt) {
    a_s[nt] = a_src[hh * FOUT + nt * 16 + l15];
    a_d[nt] = a_dst[hh * FOUT + nt * 16 + l15];
  }
#pragma unroll
  for (int q = 0; q < 4; ++q) {
    float ps = 0.f, pd = 0.f;
#pragma unroll
    for (int nt = 0; nt < 4; ++nt) {
      float tv = fast_tanh(acc[nt][q]);
      ps = fmaf(tv, a_s[nt], ps);
      pd = fmaf(tv, a_d[nt], pd);
    }
#pragma unroll
    for (int m = 8; m >= 1; m >>= 1) {
      ps += __shfl_xor(ps, m, 64);
      pd += __shfl_xor(pd, m, 64);
    }
    if (l15 == 0) {
      int row = i0 + wv * 16 + (lane >> 4) * 4 + q;
      srcb[(size_t)bh * NPTS + row] = ps;
      dstb[(size_t)bh * NPTS + row] = pd;
    }
  }

  // ---- transpose via LDS -> f16 fragment-major store
#pragma unroll
  for (int nt = 0; nt < 4; ++nt)
#pragma unroll
    for (int q = 0; q < 4; ++q)
      tile[wv * 16 + (lane >> 4) * 4 + q][nt * 16 + l15] = acc[nt][q];
  __syncthreads();

  const int cbase = t >> 6;
#pragma unroll
  for (int ci = 0; ci < 2; ++ci) {
    int cc = cbase + ci * 4;          // c = ks*4 + nt
    int ks = cc >> 2, nt2 = cc & 3;
    int jb = ks * 32 + ((lane >> 4) * 8);
    int ob = nt2 * 16 + (lane & 15);
    h8v v;
#pragma unroll
    for (int e = 0; e < 8; ++e) v[e] = (_Float16)tile[jb + e][ob];
    *(h8v*)(hfrag + (((size_t)(bh * 16 + it) * 8 + cc) * 64 + lane) * 8) = v;
  }
}

// ---------------------------------------------------------------------------
// Fused masked softmax + PV, single pass, lane-local P in f16.
// m_row = leaky(src_i + global dst max) >= true row max (monotone leaky).
// hp fragments: reg-staged global->LDS double-buffer, ONE barrier per tile.
// ---------------------------------------------------------------------------
__global__ __launch_bounds__(256, 4) void attn_kernel(
    const unsigned long long* __restrict__ abits,
    const unsigned short* __restrict__ hfrag,
    const float* __restrict__ srcb, const float* __restrict__ dstb,
    const float* __restrict__ bias, float* __restrict__ out)
{
  __shared__ float dsh[NPTS];
  __shared__ float wred[4];
  __shared__ unsigned short frag[2][4096];   // 2 x 8KB f16 fragment tiles

  const int t = threadIdx.x;
  const int lane = t & 63;
  const int wv = t >> 6;
  const int blk = blockIdx.x;
  const int it = blk & 15;
  const int hh = (blk >> 4) & 7;
  const int b  = blk >> 7;
  const int i0 = it * 64;
  const int bh = b * NH + hh;
  const int l15 = lane & 15;
  const int koff = (lane >> 4) * 8;
  const int rowA = i0 + wv * 16 + l15;        // this lane's A (P) row

  const uint4* fgb = (const uint4*)hfrag + (size_t)bh * 16 * 512;
  const uint2* abrow = (const uint2*)(abits + ((size_t)b * NPTS + rowA) * 16);

  // prologue: issue long-latency loads first
  uint4 s0 = fgb[t];
  uint4 s1 = fgb[t + 256];
  uint2 ab_cur = abrow[0];
  const float src_r = srcb[(size_t)bh * NPTS + rowA];
  float4 dv = ((const float4*)(dstb + (size_t)bh * NPTS))[t];

  ((float4*)dsh)[t] = dv;
  float lm = fmaxf(fmaxf(dv.x, dv.y), fmaxf(dv.z, dv.w));
#pragma unroll
  for (int m = 32; m >= 1; m >>= 1) lm = fmaxf(lm, __shfl_xor(lm, m, 64));
  if (lane == 0) wred[wv] = lm;
  __syncthreads();
  const float M = fmaxf(fmaxf(wred[0], wred[1]), fmaxf(wred[2], wred[3]));
  const float xm = src_r + M;
  const float m_row = fmaxf(xm, 0.2f * xm);   // leaky(src+M) >= row max

  ((uint4*)&frag[0][0])[t]       = s0;
  ((uint4*)&frag[0][0])[t + 256] = s1;
  __syncthreads();

  float l = 0.f;
  f4v acc[4];
#pragma unroll
  for (int nt = 0; nt < 4; ++nt) acc[nt] = 0.0f;

#pragma unroll 2
  for (int tt = 0; tt < 16; ++tt) {
    const int buf = tt & 1;
    uint4 n0, n1; uint2 ab_nxt;
    if (tt < 15) {                           // issue next-tile loads early
      const uint4* fgn = fgb + (size_t)(tt + 1) * 512;
      n0 = fgn[t];
      n1 = fgn[t + 256];
      ab_nxt = abrow[tt + 1];
    }

    // ---- P phase: 16 lane-local logits -> f16 A-fragments
    const int jb = tt * 64 + koff;
    float4 d0 = *(const float4*)&dsh[jb];
    float4 d1 = *(const float4*)&dsh[jb + 4];
    float4 d2 = *(const float4*)&dsh[jb + 32];
    float4 d3 = *(const float4*)&dsh[jb + 36];
    float dl0[8] = {d0.x, d0.y, d0.z, d0.w, d1.x, d1.y, d1.z, d1.w};
    float dl1[8] = {d2.x, d2.y, d2.z, d2.w, d3.x, d3.y, d3.z, d3.w};
    const unsigned w0 = ab_cur.x >> koff;
    const unsigned w1 = ab_cur.y >> koff;
    h8v pa0, pa1;
#pragma unroll
    for (int e = 0; e < 8; ++e) {
      float x = src_r + dl0[e];
      x = fmaxf(x, 0.2f * x);
      float ex = __expf(x - m_row);
      float pe = ((w0 >> e) & 1u) ? ex : 0.f;
      l += pe;
      pa0[e] = (_Float16)pe;
    }
#pragma unroll
    for (int e = 0; e < 8; ++e) {
      float x = src_r + dl1[e];
      x = fmaxf(x, 0.2f * x);
      float ex = __expf(x - m_row);
      float pe = ((w1 >> e) & 1u) ? ex : 0.f;
      l += pe;
      pa1[e] = (_Float16)pe;
    }

    // ---- MFMA phase (reads frag[buf], written last iter)
#pragma unroll
    for (int nt = 0; nt < 4; ++nt) {
      h8v B0 = *(const h8v*)&frag[buf][(nt * 64 + lane) * 8];
      acc[nt] = __builtin_amdgcn_mfma_f32_16x16x32_f16(pa0, B0, acc[nt], 0, 0, 0);
    }
#pragma unroll
    for (int nt = 0; nt < 4; ++nt) {
      h8v B1 = *(const h8v*)&frag[buf][((4 + nt) * 64 + lane) * 8];
      acc[nt] = __builtin_amdgcn_mfma_f32_16x16x32_f16(pa1, B1, acc[nt], 0, 0, 0);
    }

    // ---- stage write into the other buffer (no race: buf^1 readers passed
    //      the barrier at end of last iter), then ONE barrier
    if (tt < 15) {
      ((uint4*)&frag[buf ^ 1][0])[t]       = n0;
      ((uint4*)&frag[buf ^ 1][0])[t + 256] = n1;
      ab_cur = ab_nxt;
    }
    __syncthreads();
  }

  // ---- epilogue: denominator redistribution + normalize + bias
  l += __shfl_xor(l, 16, 64);
  l += __shfl_xor(l, 32, 64);                 // all lanes: l of row (lane&15)

  float bias4[4];
#pragma unroll
  for (int nt = 0; nt < 4; ++nt) bias4[nt] = bias[nt * 16 + l15];

#pragma unroll
  for (int q = 0; q < 4; ++q) {
    float lq = __shfl(l, (lane >> 4) * 4 + q, 64);   // lanes 0..15 hold rows 0..15
    float linv = 1.0f / lq;
    int rowq = i0 + wv * 16 + (lane >> 4) * 4 + q;
    size_t ob = ((size_t)bh * NPTS + rowq) * FOUT;
#pragma unroll
    for (int nt = 0; nt < 4; ++nt)
      out[ob + nt * 16 + l15] = acc[nt][q] * linv + bias4[nt];
  }
}

// ---------------------------------------------------------------------------
extern "C" void kernel_launch(void* const* d_in, const int* in_sizes, int n_in,
                              void* d_out, int out_size, void* d_ws, size_t ws_size,
                              hipStream_t stream)
{
  const float* h     = (const float*)d_in[0];
  const void*  adj   = d_in[1];
  const float* w     = (const float*)d_in[2];
  const float* a_src = (const float*)d_in[3];
  const float* a_dst = (const float*)d_in[4];
  const float* bias  = (const float*)d_in[5];
  float* out = (float*)d_out;

  // ws layout (16B aligned), ~10.3 MB total
  char* p = (char*)d_ws;
  int* flag = (int*)p;                          p += 256;
  float* srcb = (float*)p;                      p += (size_t)BS * NH * NPTS * 4;
  float* dstb = (float*)p;                      p += (size_t)BS * NH * NPTS * 4;
  unsigned short* wT_hi = (unsigned short*)p;   p += (size_t)NH * FOUT * FIN * 2;
  unsigned short* wT_lo = (unsigned short*)p;   p += (size_t)NH * FOUT * FIN * 2;
  unsigned long long* abits = (unsigned long long*)p;
                                                p += (size_t)BS * NPTS * 16 * 8;
  unsigned short* hfrag = (unsigned short*)p;

  detect_kernel<<<1, 256, 0, stream>>>((const unsigned int*)adj, flag);
  pack_kernel<1><<<1024, 256, 0, stream>>>(adj, flag, abits);
  pack_kernel<0><<<1024, 256, 0, stream>>>(adj, flag, abits);
  wsplit_kernel<<<NH, 256, 0, stream>>>(w, wT_hi, wT_lo);
  proj_kernel<<<dim3(BS * NH * 16), dim3(256), 0, stream>>>(
      h, wT_hi, wT_lo, a_src, a_dst, hfrag, srcb, dstb);
  attn_kernel<<<dim3(BS * NH * 16), dim3(256), 0, stream>>>(
      abits, hfrag, srcb, dstb, bias, out);
}

// Round 4
// 110.976 us; speedup vs baseline: 3.9348x; 1.0792x over previous
//
#include <hip/hip_runtime.h>
#include <math.h>

#define BS 8
#define NPTS 1024
#define NH 8
#define FIN 256
#define FOUT 64

typedef __attribute__((ext_vector_type(8))) short s8v;       // 8 bf16
typedef __attribute__((ext_vector_type(8))) _Float16 h8v;    // 8 f16
typedef __attribute__((ext_vector_type(4))) float f4v;       // 4 f32 acc

__device__ __forceinline__ unsigned short f2bf(float f) {
  unsigned u = __float_as_uint(f);
  return (unsigned short)((u + 0x7fffu + ((u >> 16) & 1u)) >> 16);
}
__device__ __forceinline__ float bf2f(unsigned short s) {
  return __uint_as_float(((unsigned)s) << 16);
}
__device__ __forceinline__ float fast_tanh(float x) {
  float e = __expf(2.f * x);          // inf-safe: x>>0 -> 1, x<<0 -> -1
  return 1.f - 2.f / (e + 1.f);
}

// ---------------------------------------------------------------------------
// prep: blocks 0..1023 = adj->bitmask pack (detect dtype in-block from the
// first 1KB, L2-broadcast); blocks 1024..1031 = w -> wT_hi/lo bf16 split.
// abits[b][i][16] u64, diagonal folded in.
// ---------------------------------------------------------------------------
__global__ __launch_bounds__(256) void prep_kernel(
    const void* __restrict__ adjv, const float* __restrict__ w,
    unsigned long long* __restrict__ abits,
    unsigned short* __restrict__ wT_hi, unsigned short* __restrict__ wT_lo)
{
  const int blk = blockIdx.x;
  const int t = threadIdx.x;
  if (blk < 1024) {
    __shared__ int badsh;
    if (t == 0) badsh = 0;
    __syncthreads();
    if (((const unsigned*)adjv)[t] > 1u) badsh = 1;   // benign race
    __syncthreads();
    const int lane = t & 63;
    const int w0 = (blk * 4 + (t >> 6)) * 32;
    if (badsh == 0) {                 // int32 {0,1} adjacency
      const int* adjI = (const int*)adjv;
#pragma unroll 8
      for (int q = 0; q < 32; ++q) {
        int wI = w0 + q;
        int b = wI >> 14, i = (wI >> 4) & 1023, ch = wI & 15;
        int j = ch * 64 + lane;
        unsigned long long m =
            __ballot(adjI[((size_t)b * NPTS + i) * NPTS + j] != 0 || j == i);
        if (lane == 0) abits[wI] = m;
      }
    } else {                          // packed byte adjacency
      const unsigned char* adjB = (const unsigned char*)adjv;
#pragma unroll 8
      for (int q = 0; q < 32; ++q) {
        int wI = w0 + q;
        int b = wI >> 14, i = (wI >> 4) & 1023, ch = wI & 15;
        int j = ch * 64 + lane;
        unsigned long long m =
            __ballot(adjB[((size_t)b * NPTS + i) * NPTS + j] != 0 || j == i);
        if (lane == 0) abits[wI] = m;
      }
    }
  } else {
    const int hh = blk - 1024;
    const int o = t & 63, kb = t >> 6;
    for (int k0 = 0; k0 < FIN; k0 += 4) {
      int k = k0 + kb;
      float v = w[((size_t)hh * FIN + k) * FOUT + o];
      unsigned short hi = f2bf(v);
      wT_hi[((size_t)hh * FOUT + o) * FIN + k] = hi;
      wT_lo[((size_t)hh * FOUT + o) * FIN + k] = f2bf(v - bf2f(hi));
    }
  }
}

// ---------------------------------------------------------------------------
// Projection via MFMA (3-term bf16 split ~ f32 precision), register-pipelined:
// h prefetched 4 k-steps deep, B fragments double-buffered in registers.
// Outputs: hfrag f16 fragment-major, srcb/dstb f32.
// ---------------------------------------------------------------------------
__global__ __launch_bounds__(256, 2) void proj_kernel(
    const float* __restrict__ h, const unsigned short* __restrict__ wT_hi,
    const unsigned short* __restrict__ wT_lo,
    const float* __restrict__ a_src, const float* __restrict__ a_dst,
    unsigned short* __restrict__ hfrag,
    float* __restrict__ srcb, float* __restrict__ dstb)
{
  __shared__ float tile[64][65];

  const int t = threadIdx.x;
  const int lane = t & 63;
  const int wv = t >> 6;
  const int blk = blockIdx.x;
  const int it = blk & 15;
  const int hh = (blk >> 4) & 7;
  const int b  = blk >> 7;
  const int i0 = it * 64;
  const int bh = b * NH + hh;
  const int l15 = lane & 15;
  const int koff = (lane >> 4) * 8;

  const float* hrow = h + ((size_t)(b * NPTS + i0 + wv * 16 + l15)) * FIN + koff;
  const unsigned short* wh = wT_hi + ((size_t)hh * FOUT + l15) * FIN + koff;
  const unsigned short* wl = wT_lo + ((size_t)hh * FOUT + l15) * FIN + koff;

  // 4-deep h prefetch (32 VGPR)
  float4 hA[4][2];
#pragma unroll
  for (int k0 = 0; k0 < 4; ++k0) {
    hA[k0][0] = *(const float4*)(hrow + k0 * 32);
    hA[k0][1] = *(const float4*)(hrow + k0 * 32 + 4);
  }
  // B double buffer (64 VGPR)
  s8v Bh[2][4], Bl[2][4];
#pragma unroll
  for (int nt = 0; nt < 4; ++nt) {
    Bh[0][nt] = *(const s8v*)(wh + (size_t)nt * 16 * FIN);
    Bl[0][nt] = *(const s8v*)(wl + (size_t)nt * 16 * FIN);
  }

  f4v acc[4];
#pragma unroll
  for (int nt = 0; nt < 4; ++nt) acc[nt] = 0.0f;

#pragma unroll
  for (int k0 = 0; k0 < 8; ++k0) {
    const int cur = k0 & 1, nxt = cur ^ 1;
    if (k0 < 7) {                     // issue next B tile early
#pragma unroll
      for (int nt = 0; nt < 4; ++nt) {
        Bh[nxt][nt] = *(const s8v*)(wh + (size_t)nt * 16 * FIN + (k0 + 1) * 32);
        Bl[nxt][nt] = *(const s8v*)(wl + (size_t)nt * 16 * FIN + (k0 + 1) * 32);
      }
    }
    // truncation split of A (exact remainder chain, ~2^-16 rel)
    const int sl = k0 & 3;
    float av[8] = {hA[sl][0].x, hA[sl][0].y, hA[sl][0].z, hA[sl][0].w,
                   hA[sl][1].x, hA[sl][1].y, hA[sl][1].z, hA[sl][1].w};
    s8v Ahi, Alo;
#pragma unroll
    for (int e = 0; e < 8; ++e) {
      unsigned u = __float_as_uint(av[e]);
      float r = av[e] - __uint_as_float(u & 0xffff0000u);
      Ahi[e] = (short)(unsigned short)(u >> 16);
      Alo[e] = (short)(unsigned short)(__float_as_uint(r) >> 16);
    }
    if (k0 < 4) {                     // refill h prefetch for k0+4
      hA[sl][0] = *(const float4*)(hrow + (k0 + 4) * 32);
      hA[sl][1] = *(const float4*)(hrow + (k0 + 4) * 32 + 4);
    }
#pragma unroll
    for (int nt = 0; nt < 4; ++nt) {
      acc[nt] = __builtin_amdgcn_mfma_f32_16x16x32_bf16(Ahi, Bh[cur][nt], acc[nt], 0, 0, 0);
      acc[nt] = __builtin_amdgcn_mfma_f32_16x16x32_bf16(Alo, Bh[cur][nt], acc[nt], 0, 0, 0);
      acc[nt] = __builtin_amdgcn_mfma_f32_16x16x32_bf16(Ahi, Bl[cur][nt], acc[nt], 0, 0, 0);
    }
  }

  // ---- attn_src / attn_dst: tanh(hp) . a
  float a_s[4], a_d[4];
#pragma unroll
  for (int nt = 0; nt < 4; ++nt) {
    a_s[nt] = a_src[hh * FOUT + nt * 16 + l15];
    a_d[nt] = a_dst[hh * FOUT + nt * 16 + l15];
  }
#pragma unroll
  for (int q = 0; q < 4; ++q) {
    float ps = 0.f, pd = 0.f;
#pragma unroll
    for (int nt = 0; nt < 4; ++nt) {
      float tv = fast_tanh(acc[nt][q]);
      ps = fmaf(tv, a_s[nt], ps);
      pd = fmaf(tv, a_d[nt], pd);
    }
#pragma unroll
    for (int m = 8; m >= 1; m >>= 1) {
      ps += __shfl_xor(ps, m, 64);
      pd += __shfl_xor(pd, m, 64);
    }
    if (l15 == 0) {
      int row = i0 + wv * 16 + (lane >> 4) * 4 + q;
      srcb[(size_t)bh * NPTS + row] = ps;
      dstb[(size_t)bh * NPTS + row] = pd;
    }
  }

  // ---- transpose via LDS -> f16 fragment-major store
#pragma unroll
  for (int nt = 0; nt < 4; ++nt)
#pragma unroll
    for (int q = 0; q < 4; ++q)
      tile[wv * 16 + (lane >> 4) * 4 + q][nt * 16 + l15] = acc[nt][q];
  __syncthreads();

  const int cbase = t >> 6;
#pragma unroll
  for (int ci = 0; ci < 2; ++ci) {
    int cc = cbase + ci * 4;          // c = ks*4 + nt
    int ks = cc >> 2, nt2 = cc & 3;
    int jb = ks * 32 + ((lane >> 4) * 8);
    int ob = nt2 * 16 + (lane & 15);
    h8v v;
#pragma unroll
    for (int e = 0; e < 8; ++e) v[e] = (_Float16)tile[jb + e][ob];
    *(h8v*)(hfrag + (((size_t)(bh * 16 + it) * 8 + cc) * 64 + lane) * 8) = v;
  }
}

// ---------------------------------------------------------------------------
// Fused masked softmax + PV, KVBLK=128 (2 sub-tiles per phase, 8 barriers).
// Lane-local P in f16; m_row = leaky(src_i + global dst max) >= row max.
// ---------------------------------------------------------------------------
__global__ __launch_bounds__(256, 4) void attn_kernel(
    const unsigned long long* __restrict__ abits,
    const unsigned short* __restrict__ hfrag,
    const float* __restrict__ srcb, const float* __restrict__ dstb,
    const float* __restrict__ bias, float* __restrict__ out)
{
  __shared__ float dsh[NPTS];
  __shared__ float wred[4];
  __shared__ unsigned short frag[2][8192];   // 2 x 16KB f16 fragment tiles

  const int t = threadIdx.x;
  const int lane = t & 63;
  const int wv = t >> 6;
  const int blk = blockIdx.x;
  const int it = blk & 15;
  const int hh = (blk >> 4) & 7;
  const int b  = blk >> 7;
  const int i0 = it * 64;
  const int bh = b * NH + hh;
  const int l15 = lane & 15;
  const int koff = (lane >> 4) * 8;
  const int rowA = i0 + wv * 16 + l15;        // this lane's P row

  const uint4* fgb = (const uint4*)hfrag + (size_t)bh * 16 * 512;
  const uint4* abrow4 = (const uint4*)(abits + ((size_t)b * NPTS + rowA) * 16);

  // prologue: issue long-latency loads first
  uint4 s0 = fgb[t];
  uint4 s1 = fgb[t + 256];
  uint4 s2 = fgb[t + 512];
  uint4 s3 = fgb[t + 768];
  uint4 ab_cur = abrow4[0];
  const float src_r = srcb[(size_t)bh * NPTS + rowA];
  float4 dv = ((const float4*)(dstb + (size_t)bh * NPTS))[t];

  ((float4*)dsh)[t] = dv;
  float lm = fmaxf(fmaxf(dv.x, dv.y), fmaxf(dv.z, dv.w));
#pragma unroll
  for (int m = 32; m >= 1; m >>= 1) lm = fmaxf(lm, __shfl_xor(lm, m, 64));
  if (lane == 0) wred[wv] = lm;
  __syncthreads();
  const float M = fmaxf(fmaxf(wred[0], wred[1]), fmaxf(wred[2], wred[3]));
  const float xm = src_r + M;
  const float m_row = fmaxf(xm, 0.2f * xm);

  {
    uint4* dstf = (uint4*)&frag[0][0];
    dstf[t] = s0; dstf[t + 256] = s1; dstf[t + 512] = s2; dstf[t + 768] = s3;
  }
  __syncthreads();

  float l = 0.f;
  f4v acc[4];
#pragma unroll
  for (int nt = 0; nt < 4; ++nt) acc[nt] = 0.0f;

#pragma unroll 2
  for (int jt = 0; jt < 8; ++jt) {
    const int buf = jt & 1;
    uint4 n0, n1, n2, n3, ab_nxt;
    if (jt < 7) {                     // next-iter loads in flight under P+MFMA
      const uint4* fgn = fgb + (size_t)(jt + 1) * 1024;
      n0 = fgn[t]; n1 = fgn[t + 256]; n2 = fgn[t + 512]; n3 = fgn[t + 768];
      ab_nxt = abrow4[jt + 1];
    }

    // ---- P phase: 32 lane-local logits -> 4 f16 A-fragments
    h8v pa[2][2];
#pragma unroll
    for (int s = 0; s < 2; ++s)
#pragma unroll
      for (int ks = 0; ks < 2; ++ks) {
        const int jb = jt * 128 + s * 64 + ks * 32 + koff;
        float4 d0 = *(const float4*)&dsh[jb];
        float4 d1 = *(const float4*)&dsh[jb + 4];
        float dl[8] = {d0.x, d0.y, d0.z, d0.w, d1.x, d1.y, d1.z, d1.w};
        unsigned w32 =
            (s ? (ks ? ab_cur.w : ab_cur.z) : (ks ? ab_cur.y : ab_cur.x)) >> koff;
        h8v pv;
#pragma unroll
        for (int e = 0; e < 8; ++e) {
          float x = src_r + dl[e];
          x = fmaxf(x, 0.2f * x);
          float ex = __expf(x - m_row);
          float pe = ((w32 >> e) & 1u) ? ex : 0.f;
          l += pe;
          pv[e] = (_Float16)pe;
        }
        pa[s][ks] = pv;
      }

    // ---- MFMA phase: 16 MFMA on frag[buf]
    __builtin_amdgcn_s_setprio(1);
#pragma unroll
    for (int s = 0; s < 2; ++s)
#pragma unroll
      for (int ks = 0; ks < 2; ++ks)
#pragma unroll
        for (int nt = 0; nt < 4; ++nt) {
          h8v B = *(const h8v*)&frag[buf][(((s * 8 + ks * 4 + nt) * 64) + lane) * 8];
          acc[nt] = __builtin_amdgcn_mfma_f32_16x16x32_f16(pa[s][ks], B, acc[nt], 0, 0, 0);
        }
    __builtin_amdgcn_s_setprio(0);

    // ---- stage write to other buffer (readers of buf^1 passed last barrier)
    if (jt < 7) {
      uint4* dstf = (uint4*)&frag[buf ^ 1][0];
      dstf[t] = n0; dstf[t + 256] = n1; dstf[t + 512] = n2; dstf[t + 768] = n3;
      ab_cur = ab_nxt;
    }
    __syncthreads();
  }

  // ---- epilogue: denominator redistribution + normalize + bias
  l += __shfl_xor(l, 16, 64);
  l += __shfl_xor(l, 32, 64);

  float bias4[4];
#pragma unroll
  for (int nt = 0; nt < 4; ++nt) bias4[nt] = bias[nt * 16 + l15];

#pragma unroll
  for (int q = 0; q < 4; ++q) {
    float lq = __shfl(l, (lane >> 4) * 4 + q, 64);
    float linv = 1.0f / lq;
    int rowq = i0 + wv * 16 + (lane >> 4) * 4 + q;
    size_t ob = ((size_t)bh * NPTS + rowq) * FOUT;
#pragma unroll
    for (int nt = 0; nt < 4; ++nt)
      out[ob + nt * 16 + l15] = acc[nt][q] * linv + bias4[nt];
  }
}

// ---------------------------------------------------------------------------
extern "C" void kernel_launch(void* const* d_in, const int* in_sizes, int n_in,
                              void* d_out, int out_size, void* d_ws, size_t ws_size,
                              hipStream_t stream)
{
  const float* h     = (const float*)d_in[0];
  const void*  adj   = d_in[1];
  const float* w     = (const float*)d_in[2];
  const float* a_src = (const float*)d_in[3];
  const float* a_dst = (const float*)d_in[4];
  const float* bias  = (const float*)d_in[5];
  float* out = (float*)d_out;

  // ws layout (16B aligned), ~10.3 MB total
  char* p = (char*)d_ws;
  float* srcb = (float*)p;                      p += (size_t)BS * NH * NPTS * 4;
  float* dstb = (float*)p;                      p += (size_t)BS * NH * NPTS * 4;
  unsigned short* wT_hi = (unsigned short*)p;   p += (size_t)NH * FOUT * FIN * 2;
  unsigned short* wT_lo = (unsigned short*)p;   p += (size_t)NH * FOUT * FIN * 2;
  unsigned long long* abits = (unsigned long long*)p;
                                                p += (size_t)BS * NPTS * 16 * 8;
  unsigned short* hfrag = (unsigned short*)p;

  prep_kernel<<<dim3(1032), dim3(256), 0, stream>>>(adj, w, abits, wT_hi, wT_lo);
  proj_kernel<<<dim3(BS * NH * 16), dim3(256), 0, stream>>>(
      h, wT_hi, wT_lo, a_src, a_dst, hfrag, srcb, dstb);
  attn_kernel<<<dim3(BS * NH * 16), dim3(256), 0, stream>>>(
      abits, hfrag, srcb, dstb, bias, out);
}

// Round 5
// 64.785 us; speedup vs baseline: 6.7402x; 1.7130x over previous
//
#include <hip/hip_runtime.h>
#include <math.h>

#define BS 8
#define NPTS 1024
#define NH 8
#define FIN 256
#define FOUT 64

typedef __attribute__((ext_vector_type(8))) short s8v;       // 8 bf16
typedef __attribute__((ext_vector_type(8))) _Float16 h8v;    // 8 f16
typedef __attribute__((ext_vector_type(4))) float f4v;       // 4 f32 acc
typedef unsigned long long u64;

__device__ __forceinline__ unsigned short f2bf(float f) {
  unsigned u = __float_as_uint(f);
  return (unsigned short)((u + 0x7fffu + ((u >> 16) & 1u)) >> 16);
}
__device__ __forceinline__ float bf2f(unsigned short s) {
  return __uint_as_float(((unsigned)s) << 16);
}
__device__ __forceinline__ float fast_tanh(float x) {
  float e = __expf(2.f * x);
  return 1.f - 2.f / (e + 1.f);
}

// ---------------------------------------------------------------------------
// prep: blocks 0..2047 = adj->bitmask pack (1 wave per row, 4 int4 loads all
// in flight, shfl-OR nibble combine); blocks 2048..2111 = w bf16 split.
// abits[b][i][16] u64, diagonal folded in.
// ---------------------------------------------------------------------------
__global__ __launch_bounds__(256) void prep_kernel(
    const void* __restrict__ adjv, const float* __restrict__ w,
    u64* __restrict__ abits,
    unsigned short* __restrict__ wT_hi, unsigned short* __restrict__ wT_lo)
{
  const int blk = blockIdx.x;
  const int t = threadIdx.x;
  if (blk < 2048) {
    __shared__ int badsh;
    if (t == 0) badsh = 0;
    __syncthreads();
    if (((const unsigned*)adjv)[t] > 1u) badsh = 1;   // dtype detect (1KB scan)
    __syncthreads();
    const int lane = t & 63;
    const int gw = blk * 4 + (t >> 6);                // row id 0..8191
    const int b = gw >> 10, i = gw & 1023;
    const int m16 = lane & 15, g = lane >> 4;
    u64 words[4];
    if (badsh == 0) {                                 // int32 {0,1} adjacency
      const int4* row4 = (const int4*)((const int*)adjv + ((size_t)b * NPTS + i) * NPTS);
      int4 av[4];
      av[0] = row4[lane]; av[1] = row4[lane + 64];
      av[2] = row4[lane + 128]; av[3] = row4[lane + 192];
#pragma unroll
      for (int ci = 0; ci < 4; ++ci) {
        unsigned n = (unsigned)(av[ci].x != 0) | ((unsigned)(av[ci].y != 0) << 1) |
                     ((unsigned)(av[ci].z != 0) << 2) | ((unsigned)(av[ci].w != 0) << 3);
        unsigned d = (unsigned)(i - (ci * 256 + 4 * lane));
        if (d < 4u) n |= 1u << d;                     // diagonal
        u64 val = (u64)n << (4 * m16);
#pragma unroll
        for (int msk = 1; msk <= 8; msk <<= 1)
          val |= (u64)__shfl_xor(val, msk, 64);
        words[ci] = val;
      }
    } else {                                          // packed byte adjacency
      const unsigned* rowB = (const unsigned*)((const unsigned char*)adjv + ((size_t)b * NPTS + i) * NPTS);
      unsigned av[4];
      av[0] = rowB[lane]; av[1] = rowB[lane + 64];
      av[2] = rowB[lane + 128]; av[3] = rowB[lane + 192];
#pragma unroll
      for (int ci = 0; ci < 4; ++ci) {
        unsigned v = av[ci];
        unsigned n = ((v & 0xffu) ? 1u : 0u) | (((v >> 8) & 0xffu) ? 2u : 0u) |
                     (((v >> 16) & 0xffu) ? 4u : 0u) | ((v >> 24) ? 8u : 0u);
        unsigned d = (unsigned)(i - (ci * 256 + 4 * lane));
        if (d < 4u) n |= 1u << d;
        u64 val = (u64)n << (4 * m16);
#pragma unroll
        for (int msk = 1; msk <= 8; msk <<= 1)
          val |= (u64)__shfl_xor(val, msk, 64);
        words[ci] = val;
      }
    }
    if (m16 == 0) {
#pragma unroll
      for (int ci = 0; ci < 4; ++ci)
        abits[((size_t)b * NPTS + i) * 16 + ci * 4 + g] = words[ci];
    }
  } else {
    const int bb = blk - 2048;
    const int hh = bb >> 3, ks = bb & 7;
    const int o = t & 63, kq = t >> 6;
#pragma unroll
    for (int e = 0; e < 8; ++e) {
      int k = ks * 32 + kq * 8 + e;
      float v = w[((size_t)hh * FIN + k) * FOUT + o];
      unsigned short hi = f2bf(v);
      wT_hi[((size_t)hh * FOUT + o) * FIN + k] = hi;
      wT_lo[((size_t)hh * FOUT + o) * FIN + k] = f2bf(v - bf2f(hi));
    }
  }
}

// ---------------------------------------------------------------------------
// Projection via MFMA (3-term bf16 split ~ f32). 128 rows/block, 32 rows/wave
// (acc[2][4]) -> B:MFMA ratio halved. Register dbuf for B, 4-deep h prefetch,
// pinned with sched_barrier(0). Outputs hfrag f16 fragment-major, srcb/dstb.
// ---------------------------------------------------------------------------
__global__ __launch_bounds__(256, 2) void proj_kernel(
    const float* __restrict__ h, const unsigned short* __restrict__ wT_hi,
    const unsigned short* __restrict__ wT_lo,
    const float* __restrict__ a_src, const float* __restrict__ a_dst,
    unsigned short* __restrict__ hfrag,
    float* __restrict__ srcb, float* __restrict__ dstb)
{
  __shared__ float tile[128][65];   // 33.3 KB

  const int t = threadIdx.x;
  const int lane = t & 63;
  const int wv = t >> 6;
  const int blk = blockIdx.x;
  const int it = blk & 7;           // 128-row tile
  const int hh = (blk >> 3) & 7;
  const int b  = blk >> 6;
  const int i0 = it * 128;
  const int bh = b * NH + hh;
  const int l15 = lane & 15;
  const int koff = (lane >> 4) * 8;

  const float* hrow0 = h + ((size_t)(b * NPTS + i0 + wv * 32 + l15)) * FIN + koff;
  const float* hrow1 = hrow0 + 16 * FIN;
  const unsigned short* wh = wT_hi + ((size_t)hh * FOUT + l15) * FIN + koff;
  const unsigned short* wl = wT_lo + ((size_t)hh * FOUT + l15) * FIN + koff;

  // 4-deep h prefetch, 2 rows
  float4 hA[4][2][2];
#pragma unroll
  for (int d = 0; d < 4; ++d) {
    hA[d][0][0] = *(const float4*)(hrow0 + d * 32);
    hA[d][0][1] = *(const float4*)(hrow0 + d * 32 + 4);
    hA[d][1][0] = *(const float4*)(hrow1 + d * 32);
    hA[d][1][1] = *(const float4*)(hrow1 + d * 32 + 4);
  }
  // B double buffer
  s8v Bh[2][4], Bl[2][4];
#pragma unroll
  for (int nt = 0; nt < 4; ++nt) {
    Bh[0][nt] = *(const s8v*)(wh + (size_t)nt * 16 * FIN);
    Bl[0][nt] = *(const s8v*)(wl + (size_t)nt * 16 * FIN);
  }
  __builtin_amdgcn_sched_barrier(0);

  f4v acc[2][4];
#pragma unroll
  for (int r = 0; r < 2; ++r)
#pragma unroll
    for (int nt = 0; nt < 4; ++nt) acc[r][nt] = 0.0f;

#pragma unroll
  for (int k0 = 0; k0 < 8; ++k0) {
    const int cur = k0 & 1, nxt = cur ^ 1;
    if (k0 < 7) {
#pragma unroll
      for (int nt = 0; nt < 4; ++nt) {
        Bh[nxt][nt] = *(const s8v*)(wh + (size_t)nt * 16 * FIN + (k0 + 1) * 32);
        Bl[nxt][nt] = *(const s8v*)(wl + (size_t)nt * 16 * FIN + (k0 + 1) * 32);
      }
    }
    __builtin_amdgcn_sched_barrier(0);   // pin loads above

    const int sl = k0 & 3;
    s8v Ahi[2], Alo[2];
#pragma unroll
    for (int r = 0; r < 2; ++r) {
      float av[8] = {hA[sl][r][0].x, hA[sl][r][0].y, hA[sl][r][0].z, hA[sl][r][0].w,
                     hA[sl][r][1].x, hA[sl][r][1].y, hA[sl][r][1].z, hA[sl][r][1].w};
#pragma unroll
      for (int e = 0; e < 8; ++e) {
        unsigned u = __float_as_uint(av[e]);
        float rr = av[e] - __uint_as_float(u & 0xffff0000u);
        Ahi[r][e] = (short)(unsigned short)(u >> 16);
        Alo[r][e] = (short)(unsigned short)(__float_as_uint(rr) >> 16);
      }
    }
    if (k0 < 4) {                       // refill h prefetch for k0+4
      hA[sl][0][0] = *(const float4*)(hrow0 + (k0 + 4) * 32);
      hA[sl][0][1] = *(const float4*)(hrow0 + (k0 + 4) * 32 + 4);
      hA[sl][1][0] = *(const float4*)(hrow1 + (k0 + 4) * 32);
      hA[sl][1][1] = *(const float4*)(hrow1 + (k0 + 4) * 32 + 4);
    }
    __builtin_amdgcn_sched_barrier(0);   // pin refills above MFMA cluster

#pragma unroll
    for (int r = 0; r < 2; ++r)
#pragma unroll
      for (int nt = 0; nt < 4; ++nt) {
        acc[r][nt] = __builtin_amdgcn_mfma_f32_16x16x32_bf16(Ahi[r], Bh[cur][nt], acc[r][nt], 0, 0, 0);
        acc[r][nt] = __builtin_amdgcn_mfma_f32_16x16x32_bf16(Alo[r], Bh[cur][nt], acc[r][nt], 0, 0, 0);
        acc[r][nt] = __builtin_amdgcn_mfma_f32_16x16x32_bf16(Ahi[r], Bl[cur][nt], acc[r][nt], 0, 0, 0);
      }
  }

  // ---- attn_src / attn_dst: tanh(hp) . a
  float a_s[4], a_d[4];
#pragma unroll
  for (int nt = 0; nt < 4; ++nt) {
    a_s[nt] = a_src[hh * FOUT + nt * 16 + l15];
    a_d[nt] = a_dst[hh * FOUT + nt * 16 + l15];
  }
#pragma unroll
  for (int r = 0; r < 2; ++r)
#pragma unroll
    for (int q = 0; q < 4; ++q) {
      float ps = 0.f, pd = 0.f;
#pragma unroll
      for (int nt = 0; nt < 4; ++nt) {
        float tv = fast_tanh(acc[r][nt][q]);
        ps = fmaf(tv, a_s[nt], ps);
        pd = fmaf(tv, a_d[nt], pd);
      }
#pragma unroll
      for (int m = 8; m >= 1; m >>= 1) {
        ps += __shfl_xor(ps, m, 64);
        pd += __shfl_xor(pd, m, 64);
      }
      if (l15 == 0) {
        int row = i0 + wv * 32 + r * 16 + (lane >> 4) * 4 + q;
        srcb[(size_t)bh * NPTS + row] = ps;
        dstb[(size_t)bh * NPTS + row] = pd;
      }
    }

  // ---- transpose via LDS -> f16 fragment-major store (2 x 64-row halves)
#pragma unroll
  for (int r = 0; r < 2; ++r)
#pragma unroll
    for (int nt = 0; nt < 4; ++nt)
#pragma unroll
      for (int q = 0; q < 4; ++q)
        tile[wv * 32 + r * 16 + (lane >> 4) * 4 + q][nt * 16 + l15] = acc[r][nt][q];
  __syncthreads();

  const int cbase = t >> 6;
#pragma unroll
  for (int hf = 0; hf < 2; ++hf) {
    const int jt64 = it * 2 + hf;
#pragma unroll
    for (int ci = 0; ci < 2; ++ci) {
      int cc = cbase + ci * 4;        // cc = ks*4 + nt
      int ks = cc >> 2, nt2 = cc & 3;
      int jb = hf * 64 + ks * 32 + ((lane >> 4) * 8);
      int ob = nt2 * 16 + l15;
      h8v v;
#pragma unroll
      for (int e = 0; e < 8; ++e) v[e] = (_Float16)tile[jb + e][ob];
      *(h8v*)(hfrag + (((size_t)(bh * 16 + jt64) * 8 + cc) * 64 + lane) * 8) = v;
    }
  }
}

// ---------------------------------------------------------------------------
// Fused masked softmax + PV, KVBLK=64 (16 phases), lane-local P in f16,
// staging loads pinned early via sched_barrier(0).
// ---------------------------------------------------------------------------
__global__ __launch_bounds__(256, 4) void attn_kernel(
    const u64* __restrict__ abits,
    const unsigned short* __restrict__ hfrag,
    const float* __restrict__ srcb, const float* __restrict__ dstb,
    const float* __restrict__ bias, float* __restrict__ out)
{
  __shared__ float dsh[NPTS];
  __shared__ float wred[4];
  __shared__ unsigned short frag[2][4096];   // 2 x 8KB f16 fragment tiles

  const int t = threadIdx.x;
  const int lane = t & 63;
  const int wv = t >> 6;
  const int blk = blockIdx.x;
  const int it = blk & 15;
  const int hh = (blk >> 4) & 7;
  const int b  = blk >> 7;
  const int i0 = it * 64;
  const int bh = b * NH + hh;
  const int l15 = lane & 15;
  const int koff = (lane >> 4) * 8;
  const int rowA = i0 + wv * 16 + l15;

  const uint4* fgb = (const uint4*)hfrag + (size_t)bh * 16 * 512;
  const u64* abrow = abits + ((size_t)b * NPTS + rowA) * 16;

  uint4 s0 = fgb[t];
  uint4 s1 = fgb[t + 256];
  u64 ab_cur = abrow[0];
  const float src_r = srcb[(size_t)bh * NPTS + rowA];
  float4 dv = ((const float4*)(dstb + (size_t)bh * NPTS))[t];

  ((float4*)dsh)[t] = dv;
  float lm = fmaxf(fmaxf(dv.x, dv.y), fmaxf(dv.z, dv.w));
#pragma unroll
  for (int m = 32; m >= 1; m >>= 1) lm = fmaxf(lm, __shfl_xor(lm, m, 64));
  if (lane == 0) wred[wv] = lm;
  __syncthreads();
  const float M = fmaxf(fmaxf(wred[0], wred[1]), fmaxf(wred[2], wred[3]));
  const float xm = src_r + M;
  const float m_row = fmaxf(xm, 0.2f * xm);
  const float c1 = src_r - m_row;            // x>=0 branch: arg = c1 + d
  const float c2 = 0.2f * src_r - m_row;     // x<0 branch:  arg = 0.2d + c2

  ((uint4*)&frag[0][0])[t]       = s0;
  ((uint4*)&frag[0][0])[t + 256] = s1;
  __syncthreads();

  float l = 0.f;
  f4v acc[4];
#pragma unroll
  for (int nt = 0; nt < 4; ++nt) acc[nt] = 0.0f;

#pragma unroll 2
  for (int jt = 0; jt < 16; ++jt) {
    const int buf = jt & 1;
    uint4 n0, n1; u64 ab_nxt;
    if (jt < 15) {
      const uint4* fgn = fgb + (size_t)(jt + 1) * 512;
      n0 = fgn[t];
      n1 = fgn[t + 256];
      ab_nxt = abrow[jt + 1];
    }
    __builtin_amdgcn_sched_barrier(0);       // pin staging loads above

    // ---- P phase: 16 lane-local logits -> 2 f16 A-fragments
    const int jb = jt * 64 + koff;
    float4 d0 = *(const float4*)&dsh[jb];
    float4 d1 = *(const float4*)&dsh[jb + 4];
    float4 d2 = *(const float4*)&dsh[jb + 32];
    float4 d3 = *(const float4*)&dsh[jb + 36];
    float dl0[8] = {d0.x, d0.y, d0.z, d0.w, d1.x, d1.y, d1.z, d1.w};
    float dl1[8] = {d2.x, d2.y, d2.z, d2.w, d3.x, d3.y, d3.z, d3.w};
    const unsigned w0 = (unsigned)(ab_cur) >> koff;
    const unsigned w1 = (unsigned)(ab_cur >> 32) >> koff;
    h8v pa0, pa1;
#pragma unroll
    for (int e = 0; e < 8; ++e) {
      float arg = fmaxf(c1 + dl0[e], fmaf(0.2f, dl0[e], c2));
      arg = ((w0 >> e) & 1u) ? arg : -__builtin_inff();
      float pe = __expf(arg);
      l += pe;
      pa0[e] = (_Float16)pe;
    }
#pragma unroll
    for (int e = 0; e < 8; ++e) {
      float arg = fmaxf(c1 + dl1[e], fmaf(0.2f, dl1[e], c2));
      arg = ((w1 >> e) & 1u) ? arg : -__builtin_inff();
      float pe = __expf(arg);
      l += pe;
      pa1[e] = (_Float16)pe;
    }

    // ---- MFMA phase
    __builtin_amdgcn_s_setprio(1);
#pragma unroll
    for (int nt = 0; nt < 4; ++nt) {
      h8v B0 = *(const h8v*)&frag[buf][(nt * 64 + lane) * 8];
      acc[nt] = __builtin_amdgcn_mfma_f32_16x16x32_f16(pa0, B0, acc[nt], 0, 0, 0);
    }
#pragma unroll
    for (int nt = 0; nt < 4; ++nt) {
      h8v B1 = *(const h8v*)&frag[buf][((4 + nt) * 64 + lane) * 8];
      acc[nt] = __builtin_amdgcn_mfma_f32_16x16x32_f16(pa1, B1, acc[nt], 0, 0, 0);
    }
    __builtin_amdgcn_s_setprio(0);

    if (jt < 15) {
      ((uint4*)&frag[buf ^ 1][0])[t]       = n0;
      ((uint4*)&frag[buf ^ 1][0])[t + 256] = n1;
      ab_cur = ab_nxt;
    }
    __syncthreads();
  }

  // ---- epilogue
  l += __shfl_xor(l, 16, 64);
  l += __shfl_xor(l, 32, 64);

  float bias4[4];
#pragma unroll
  for (int nt = 0; nt < 4; ++nt) bias4[nt] = bias[nt * 16 + l15];

#pragma unroll
  for (int q = 0; q < 4; ++q) {
    float lq = __shfl(l, (lane >> 4) * 4 + q, 64);
    float linv = 1.0f / lq;
    int rowq = i0 + wv * 16 + (lane >> 4) * 4 + q;
    size_t ob = ((size_t)bh * NPTS + rowq) * FOUT;
#pragma unroll
    for (int nt = 0; nt < 4; ++nt)
      out[ob + nt * 16 + l15] = acc[nt][q] * linv + bias4[nt];
  }
}

// ---------------------------------------------------------------------------
extern "C" void kernel_launch(void* const* d_in, const int* in_sizes, int n_in,
                              void* d_out, int out_size, void* d_ws, size_t ws_size,
                              hipStream_t stream)
{
  const float* h     = (const float*)d_in[0];
  const void*  adj   = d_in[1];
  const float* w     = (const float*)d_in[2];
  const float* a_src = (const float*)d_in[3];
  const float* a_dst = (const float*)d_in[4];
  const float* bias  = (const float*)d_in[5];
  float* out = (float*)d_out;

  char* p = (char*)d_ws;
  float* srcb = (float*)p;                      p += (size_t)BS * NH * NPTS * 4;
  float* dstb = (float*)p;                      p += (size_t)BS * NH * NPTS * 4;
  unsigned short* wT_hi = (unsigned short*)p;   p += (size_t)NH * FOUT * FIN * 2;
  unsigned short* wT_lo = (unsigned short*)p;   p += (size_t)NH * FOUT * FIN * 2;
  u64* abits = (u64*)p;                         p += (size_t)BS * NPTS * 16 * 8;
  unsigned short* hfrag = (unsigned short*)p;

  prep_kernel<<<dim3(2112), dim3(256), 0, stream>>>(adj, w, abits, wT_hi, wT_lo);
  proj_kernel<<<dim3(BS * NH * 8), dim3(256), 0, stream>>>(
      h, wT_hi, wT_lo, a_src, a_dst, hfrag, srcb, dstb);
  attn_kernel<<<dim3(BS * NH * 16), dim3(256), 0, stream>>>(
      abits, hfrag, srcb, dstb, bias, out);
}